// Round 5
// baseline (362.328 us; speedup 1.0000x reference)
//
#include <hip/hip_runtime.h>

#define B_ROWS 524288
#define C_CLS  128
#define CONF_PEN 0.5f
#define PROB_THRESH 0.2f
#define WEIGHT_THRESH 1.0f

#define BLOCKS 2048
#define THREADS 256
#define WPB (THREADS / 64)
#define PAIRS 4                        // row-pairs per wave per iteration (8 rows)
#define NWAVES (BLOCKS * WPB)          // 8192
#define SWEEP (NWAVES * 2 * PAIRS)     // 65536 rows per sweep
#define ITERS (B_ROWS / SWEEP)         // 8, exact

// Butterfly sum: 4 DPP steps on the VALU pipe + one xor16 shuffle.
template <int CTRL>
__device__ __forceinline__ float dpp_add(float x) {
    int y = __builtin_amdgcn_update_dpp(0, __float_as_int(x), CTRL, 0xF, 0xF, true);
    return x + __int_as_float(y);
}
__device__ __forceinline__ float sum32(float s) {
    s = dpp_add<0xB1>(s);    // + lane^1
    s = dpp_add<0x4E>(s);    // + lane^2
    s = dpp_add<0x141>(s);   // + lane^4 (row_half_mirror; quads uniform)
    s = dpp_add<0x140>(s);   // + lane^8 (row_mirror; octs uniform)
    s += __shfl_xor(s, 16);
    return s;
}

// d_ws layout: partial[3*b + {0,1,2}] = {base_sum, pen_sum, count} per block
__global__ __launch_bounds__(THREADS) void afl_main(
    const float* __restrict__ outputs,
    const int* __restrict__ labels,
    const float* __restrict__ cw,
    float* __restrict__ partial) {

    const int lane = threadIdx.x & 63;
    const int wave = threadIdx.x >> 6;
    const int half = lane >> 5;          // which row of each pair
    const int sub  = lane & 31;          // lane within 32-lane half
    const int gwave = blockIdx.x * WPB + wave;
    const int row0  = gwave * (2 * PAIRS);

    float base_acc = 0.0f, pen_acc = 0.0f, cnt_acc = 0.0f;

    for (int it = 0; it < ITERS; ++it) {
        const int base = row0 + it * SWEEP;

        // ---- ONE broadcast label load for all 8 rows of this iteration ----
        const int labv = labels[base + (lane & 7)];

        // ---- streaming v-loads: each instr reads 1 KB contiguous (copy pattern) ----
        float4 v[PAIRS];
        #pragma unroll
        for (int j = 0; j < PAIRS; ++j)
            v[j] = ((const float4*)(outputs + (size_t)(base + 2 * j + half) * C_CLS))[sub];

        #pragma unroll
        for (int j = 0; j < PAIRS; ++j) {
            const int lab = __shfl(labv, 2 * j + half);   // labels[base+2j+half]

            const float e0 = __expf(v[j].x);
            const float e1 = __expf(v[j].y);
            const float e2 = __expf(v[j].z);
            const float e3 = __expf(v[j].w);
            float s = (e0 + e1) + (e2 + e3);
            s = sum32(s);

            const float thr   = PROB_THRESH * s;          // p>0.2 <=> e>0.2*s
            const float inv_s = __builtin_amdgcn_rcpf(s);

            // base CE: lane holding the label column contributes logZ - x_label
            if ((lab >> 2) == sub) {
                const float xl = (lab & 2) ? ((lab & 1) ? v[j].w : v[j].z)
                                           : ((lab & 1) ? v[j].y : v[j].x);
                base_acc += __logf(s) - xl;
            }

            // confusion penalty: p>0.2 is sparse (<=4 classes/row can pass),
            // so the cw lookup is a rare exec-masked dword load, not a bulk gather.
            const int c0 = 4 * sub;
            const float* cwrow = cw + (size_t)lab * C_CLS;
            float ps = 0.0f;
            if (e0 > thr && c0 + 0 != lab) {
                const float wv = cwrow[c0 + 0];
                if (wv > WEIGHT_THRESH) { ps = fmaf(wv, e0, ps); cnt_acc += 1.0f; }
            }
            if (e1 > thr && c0 + 1 != lab) {
                const float wv = cwrow[c0 + 1];
                if (wv > WEIGHT_THRESH) { ps = fmaf(wv, e1, ps); cnt_acc += 1.0f; }
            }
            if (e2 > thr && c0 + 2 != lab) {
                const float wv = cwrow[c0 + 2];
                if (wv > WEIGHT_THRESH) { ps = fmaf(wv, e2, ps); cnt_acc += 1.0f; }
            }
            if (e3 > thr && c0 + 3 != lab) {
                const float wv = cwrow[c0 + 3];
                if (wv > WEIGHT_THRESH) { ps = fmaf(wv, e3, ps); cnt_acc += 1.0f; }
            }
            pen_acc = fmaf(ps, inv_s, pen_acc);
        }
    }

    // ---- wave + block reduction ----
    #pragma unroll
    for (int off = 32; off >= 1; off >>= 1) {
        base_acc += __shfl_xor(base_acc, off);
        pen_acc  += __shfl_xor(pen_acc, off);
        cnt_acc  += __shfl_xor(cnt_acc, off);
    }

    __shared__ float s_base[WPB], s_pen[WPB], s_cnt[WPB];
    if (lane == 0) { s_base[wave] = base_acc; s_pen[wave] = pen_acc; s_cnt[wave] = cnt_acc; }
    __syncthreads();
    if (threadIdx.x == 0) {
        float b = 0.0f, pn = 0.0f, c = 0.0f;
        #pragma unroll
        for (int i = 0; i < WPB; ++i) { b += s_base[i]; pn += s_pen[i]; c += s_cnt[i]; }
        partial[3 * blockIdx.x + 0] = b;
        partial[3 * blockIdx.x + 1] = pn;
        partial[3 * blockIdx.x + 2] = c;
    }
}

__global__ __launch_bounds__(256) void afl_finalize(
    const float* __restrict__ partial, float* __restrict__ out) {
    float b = 0.0f, pn = 0.0f, c = 0.0f;
    for (int i = threadIdx.x; i < BLOCKS; i += 256) {
        b  += partial[3 * i + 0];
        pn += partial[3 * i + 1];
        c  += partial[3 * i + 2];
    }
    #pragma unroll
    for (int off = 32; off >= 1; off >>= 1) {
        b  += __shfl_xor(b, off);
        pn += __shfl_xor(pn, off);
        c  += __shfl_xor(c, off);
    }
    __shared__ float sb[4], sp[4], sc[4];
    const int wave = threadIdx.x >> 6;
    if ((threadIdx.x & 63) == 0) { sb[wave] = b; sp[wave] = pn; sc[wave] = c; }
    __syncthreads();
    if (threadIdx.x == 0) {
        b  = sb[0] + sb[1] + sb[2] + sb[3];
        pn = sp[0] + sp[1] + sp[2] + sp[3];
        c  = sc[0] + sc[1] + sc[2] + sc[3];
        const float penalty = (c > 0.0f) ? (pn / c) : 0.0f;
        out[0] = b * (1.0f / (float)B_ROWS) + CONF_PEN * penalty;
    }
}

extern "C" void kernel_launch(void* const* d_in, const int* in_sizes, int n_in,
                              void* d_out, int out_size, void* d_ws, size_t ws_size,
                              hipStream_t stream) {
    const float* outputs = (const float*)d_in[0];
    const int*   labels  = (const int*)d_in[1];
    const float* cw      = (const float*)d_in[2];
    float* out     = (float*)d_out;
    float* partial = (float*)d_ws;

    afl_main<<<BLOCKS, THREADS, 0, stream>>>(outputs, labels, cw, partial);
    afl_finalize<<<1, 256, 0, stream>>>(partial, out);
}